// Round 1
// baseline (445.436 us; speedup 1.0000x reference)
//
#include <hip/hip_runtime.h>
#include <hip/hip_bf16.h>
#include <stdint.h>

#define B_  256
#define L_  256
#define S_  253
#define SP_ 256   // padded S
#define D_  768
#define H_  128

typedef __bf16 bf16x8 __attribute__((ext_vector_type(8)));
typedef float  f32x4  __attribute__((ext_vector_type(4)));

__device__ __forceinline__ ushort f2bf(float f) {
  union { float f; uint32_t u; } v; v.f = f;
  uint32_t r = v.u + 0x7FFFu + ((v.u >> 16) & 1u);  // RNE
  return (ushort)(r >> 16);
}

__device__ __forceinline__ void gload16(const void* g, void* l) {
  __builtin_amdgcn_global_load_lds((const __attribute__((address_space(1))) void*)g,
                                   (__attribute__((address_space(3))) void*)l,
                                   16, 0, 0);
}

// ---------------- k0: Mt[i][j] = sum_t WK[i,t] * WQ[j,t]  (bf16 out) --------
// i = output column of qm-GEMM (rows of WK), j = reduction index (rows of WQ)
__global__ __launch_bounds__(256) void k_mt(const float* __restrict__ WK,
                                            const float* __restrict__ WQ,
                                            ushort* __restrict__ Mt) {
  int bid = blockIdx.x;
  int i0 = (bid / 3) * 4;
  int j  = (bid % 3) * 256 + threadIdx.x;
  const float4* wq  = (const float4*)(WQ + (size_t)j * D_);
  const float4* wk0 = (const float4*)(WK + (size_t)(i0 + 0) * D_);
  const float4* wk1 = (const float4*)(WK + (size_t)(i0 + 1) * D_);
  const float4* wk2 = (const float4*)(WK + (size_t)(i0 + 2) * D_);
  const float4* wk3 = (const float4*)(WK + (size_t)(i0 + 3) * D_);
  float a0 = 0.f, a1 = 0.f, a2 = 0.f, a3 = 0.f;
#pragma unroll 4
  for (int t = 0; t < D_ / 4; ++t) {
    float4 q = wq[t];
    float4 k0 = wk0[t], k1 = wk1[t], k2 = wk2[t], k3 = wk3[t];
    a0 += q.x * k0.x + q.y * k0.y + q.z * k0.z + q.w * k0.w;
    a1 += q.x * k1.x + q.y * k1.y + q.z * k1.z + q.w * k1.w;
    a2 += q.x * k2.x + q.y * k2.y + q.z * k2.z + q.w * k2.w;
    a3 += q.x * k3.x + q.y * k3.y + q.z * k3.z + q.w * k3.w;
  }
  Mt[(size_t)(i0 + 0) * D_ + j] = f2bf(a0);
  Mt[(size_t)(i0 + 1) * D_ + j] = f2bf(a1);
  Mt[(size_t)(i0 + 2) * D_ + j] = f2bf(a2);
  Mt[(size_t)(i0 + 3) * D_ + j] = f2bf(a3);
}

// ---------------- k1: cand -> bf16 (padded), w[b,s] = mask * (cand . WV) ----
__global__ __launch_bounds__(256) void k_cand(const float* __restrict__ cand,
                                              const int* __restrict__ cand_mask,
                                              const float* __restrict__ WV,
                                              ushort* __restrict__ candb,
                                              float* __restrict__ wbuf) {
  int r = blockIdx.x * 4 + (threadIdx.x >> 6);  // padded row id, one wave per row
  int l = threadIdx.x & 63;
  int b = r >> 8, s = r & 255;
  float acc = 0.f;
  ushort* dst = candb + (size_t)r * D_;
  if (s < S_) {
    const float* src = cand + ((size_t)b * S_ + s) * D_;
#pragma unroll
    for (int i = 0; i < D_ / 64; ++i) {
      int d = i * 64 + l;
      float c = src[d];
      acc += c * WV[d];
      dst[d] = f2bf(c);
    }
  } else {
#pragma unroll
    for (int i = 0; i < D_ / 64; ++i) dst[i * 64 + l] = 0;
  }
#pragma unroll
  for (int off = 32; off > 0; off >>= 1) acc += __shfl_down(acc, off, 64);
  if (l == 0) {
    float wv = 0.f;
    if (s < S_ && cand_mask[(size_t)b * S_ + s] != 0) wv = acc;
    wbuf[r] = wv;
  }
}

// ---------------- k2: qm[r][c] = sum_k ctx[r][k] * Mt[c][k]  (bf16 out) -----
// 128x128 tile, BK=32, 4 waves (2x2), each wave 64x64 = 4x4 fragments.
__global__ __launch_bounds__(256) void k_qm(const float* __restrict__ ctx,
                                            const ushort* __restrict__ Mt,
                                            ushort* __restrict__ qm) {
  __shared__ __align__(16) ushort As[128 * 32];
  __shared__ __align__(16) ushort Bs[128 * 32];
  int bid = blockIdx.x;
  int bm = bid / 6, bn = bid % 6;
  int row0 = bm * 128, col0 = bn * 128;
  int tid = threadIdx.x;
  int w = tid >> 6, l = tid & 63;
  int wr = w >> 1, wc = w & 1;

  // A staging: thread stages 16 f32 -> 16 bf16. row = tid/2, k-half = tid&1.
  int ar = tid >> 1;
  int ah = tid & 1;
  const float* actx = ctx + (size_t)(row0 + ar) * D_ + ah * 16;
  char* a_lds = (char*)As + ar * 64 + ah * 32;

  f32x4 acc[4][4];
#pragma unroll
  for (int m = 0; m < 4; ++m)
#pragma unroll
    for (int n = 0; n < 4; ++n) acc[m][n] = (f32x4){0.f, 0.f, 0.f, 0.f};

  for (int kt = 0; kt < D_; kt += 32) {
    if (kt) __syncthreads();
    // B: async global->LDS, 2 insts/wave, 16 rows (1KB) each
#pragma unroll
    for (int g = 0; g < 2; ++g) {
      int grp = w * 2 + g;
      const ushort* gsrc = Mt + (size_t)(col0 + grp * 16 + (l >> 2)) * D_ + kt + (l & 3) * 8;
      gload16(gsrc, (char*)Bs + grp * 1024);
    }
    // A: reg-staged f32 -> bf16
    {
      const float4* ap = (const float4*)(actx + kt);
      float4 f0 = ap[0], f1 = ap[1], f2 = ap[2], f3 = ap[3];
      uint4 w0, w1;
      w0.x = (uint32_t)f2bf(f0.x) | ((uint32_t)f2bf(f0.y) << 16);
      w0.y = (uint32_t)f2bf(f0.z) | ((uint32_t)f2bf(f0.w) << 16);
      w0.z = (uint32_t)f2bf(f1.x) | ((uint32_t)f2bf(f1.y) << 16);
      w0.w = (uint32_t)f2bf(f1.z) | ((uint32_t)f2bf(f1.w) << 16);
      w1.x = (uint32_t)f2bf(f2.x) | ((uint32_t)f2bf(f2.y) << 16);
      w1.y = (uint32_t)f2bf(f2.z) | ((uint32_t)f2bf(f2.w) << 16);
      w1.z = (uint32_t)f2bf(f3.x) | ((uint32_t)f2bf(f3.y) << 16);
      w1.w = (uint32_t)f2bf(f3.z) | ((uint32_t)f2bf(f3.w) << 16);
      *(uint4*)(a_lds)      = w0;
      *(uint4*)(a_lds + 16) = w1;
    }
    __syncthreads();

    bf16x8 af[4], bfr[4];
#pragma unroll
    for (int m = 0; m < 4; ++m)
      af[m] = *(const bf16x8*)&As[(wr * 64 + m * 16 + (l & 15)) * 32 + (l >> 4) * 8];
#pragma unroll
    for (int n = 0; n < 4; ++n)
      bfr[n] = *(const bf16x8*)&Bs[(wc * 64 + n * 16 + (l & 15)) * 32 + (l >> 4) * 8];
#pragma unroll
    for (int m = 0; m < 4; ++m)
#pragma unroll
      for (int n = 0; n < 4; ++n)
        acc[m][n] = __builtin_amdgcn_mfma_f32_16x16x32_bf16(af[m], bfr[n], acc[m][n], 0, 0, 0);
  }

  int rbase = row0 + wr * 64;
  int cbase = col0 + wc * 64;
#pragma unroll
  for (int m = 0; m < 4; ++m)
#pragma unroll
    for (int n = 0; n < 4; ++n)
#pragma unroll
      for (int i = 0; i < 4; ++i) {
        int rr = rbase + m * 16 + (l >> 4) * 4 + i;
        int cc = cbase + n * 16 + (l & 15);
        qm[(size_t)rr * D_ + cc] = f2bf(acc[m][n][i]);
      }
}

// ---------------- k3: logits -> sigmoid -> * w -> row-sum -> x --------------
// block = (b, 64-row L tile). BM=64, BN=256 (S padded), BK=32, 4 waves (1x4).
__global__ __launch_bounds__(256) void k_attn(const ushort* __restrict__ qm,
                                              const ushort* __restrict__ candb,
                                              const float* __restrict__ wbuf,
                                              const int* __restrict__ ctx_mask,
                                              float* __restrict__ xbuf) {
  __shared__ __align__(16) ushort As[64 * 32];
  __shared__ __align__(16) ushort Bs[256 * 32];
  __shared__ float w_lds[256];
  __shared__ float xpart[4][64];
  int bid = blockIdx.x;
  int b = bid >> 2, lt = bid & 3;
  int row0 = lt * 64;
  int tid = threadIdx.x, w = tid >> 6, l = tid & 63;
  w_lds[tid] = wbuf[(size_t)b * 256 + tid];

  f32x4 acc[4][4];
#pragma unroll
  for (int m = 0; m < 4; ++m)
#pragma unroll
    for (int n = 0; n < 4; ++n) acc[m][n] = (f32x4){0.f, 0.f, 0.f, 0.f};

  size_t arow = (size_t)b * 256 + row0;
  size_t brow = (size_t)b * 256;

  for (int kt = 0; kt < D_; kt += 32) {
    if (kt) __syncthreads();
    // A: 1 gload/wave (16 rows)
    {
      const ushort* gsrc = qm + (arow + w * 16 + (l >> 2)) * D_ + kt + (l & 3) * 8;
      gload16(gsrc, (char*)As + w * 1024);
    }
    // B: 4 gloads/wave (64 rows)
#pragma unroll
    for (int g = 0; g < 4; ++g) {
      int grp = w * 4 + g;
      const ushort* gsrc = candb + (brow + grp * 16 + (l >> 2)) * D_ + kt + (l & 3) * 8;
      gload16(gsrc, (char*)Bs + grp * 1024);
    }
    __syncthreads();

    bf16x8 af[4], bfr[4];
#pragma unroll
    for (int m = 0; m < 4; ++m)
      af[m] = *(const bf16x8*)&As[(m * 16 + (l & 15)) * 32 + (l >> 4) * 8];
#pragma unroll
    for (int n = 0; n < 4; ++n)
      bfr[n] = *(const bf16x8*)&Bs[(w * 64 + n * 16 + (l & 15)) * 32 + (l >> 4) * 8];
#pragma unroll
    for (int m = 0; m < 4; ++m)
#pragma unroll
      for (int n = 0; n < 4; ++n)
        acc[m][n] = __builtin_amdgcn_mfma_f32_16x16x32_bf16(af[m], bfr[n], acc[m][n], 0, 0, 0);
  }

  const float scale = 0.03608439182435161f;  // 1/sqrt(768)
  float rs[4][4];
#pragma unroll
  for (int m = 0; m < 4; ++m)
#pragma unroll
    for (int i = 0; i < 4; ++i) rs[m][i] = 0.f;

#pragma unroll
  for (int n = 0; n < 4; ++n) {
    float wcol = w_lds[w * 64 + n * 16 + (l & 15)];
#pragma unroll
    for (int m = 0; m < 4; ++m)
#pragma unroll
      for (int i = 0; i < 4; ++i) {
        float p = 1.f / (1.f + __expf(-acc[m][n][i] * scale));
        rs[m][i] += p * wcol;
      }
  }
#pragma unroll
  for (int m = 0; m < 4; ++m)
#pragma unroll
    for (int i = 0; i < 4; ++i) {
      float v = rs[m][i];
      v += __shfl_xor(v, 1, 64);
      v += __shfl_xor(v, 2, 64);
      v += __shfl_xor(v, 4, 64);
      v += __shfl_xor(v, 8, 64);
      rs[m][i] = v;
    }
  if ((l & 15) == 0) {
#pragma unroll
    for (int m = 0; m < 4; ++m)
#pragma unroll
      for (int i = 0; i < 4; ++i)
        xpart[w][m * 16 + (l >> 4) * 4 + i] = rs[m][i];
  }
  __syncthreads();
  if (tid < 64) {
    float xs = xpart[0][tid] + xpart[1][tid] + xpart[2][tid] + xpart[3][tid];
    int gm = ctx_mask[(size_t)b * 256 + row0 + tid];
    xbuf[(size_t)b * 256 + row0 + tid] = gm ? xs : 0.f;
  }
}

// ---------------- k4: y[b] = (x[b]^T W1 + b1) W2 + b2 ----------------------
__global__ __launch_bounds__(128) void k_mlp(const float* __restrict__ xbuf,
                                             const float* __restrict__ W1,
                                             const float* __restrict__ b1,
                                             const float* __restrict__ W2,
                                             const float* __restrict__ b2,
                                             float* __restrict__ out) {
  int b = blockIdx.x, t = threadIdx.x;
  __shared__ float xl[256];
  __shared__ float hl[128];
  xl[t]       = xbuf[(size_t)b * 256 + t];
  xl[t + 128] = xbuf[(size_t)b * 256 + 128 + t];
  __syncthreads();
  float acc = b1[t];
#pragma unroll 8
  for (int ll = 0; ll < 256; ++ll) acc += xl[ll] * W1[ll * H_ + t];
  hl[t] = acc;
  __syncthreads();
  if (t < 5) {
    float y = b2[t];
#pragma unroll 8
    for (int h = 0; h < H_; ++h) y += hl[h] * W2[h * 5 + t];
    out[(size_t)b * 5 + t] = y;
  }
}

extern "C" void kernel_launch(void* const* d_in, const int* in_sizes, int n_in,
                              void* d_out, int out_size, void* d_ws, size_t ws_size,
                              hipStream_t stream) {
  const float* ctx       = (const float*)d_in[0];
  const float* cand      = (const float*)d_in[1];
  const int*   ctx_mask  = (const int*)d_in[2];
  const int*   cand_mask = (const int*)d_in[3];
  const float* WK        = (const float*)d_in[4];
  const float* WQ        = (const float*)d_in[5];
  const float* WV        = (const float*)d_in[6];
  const float* W1        = (const float*)d_in[7];
  const float* b1        = (const float*)d_in[8];
  const float* W2        = (const float*)d_in[9];
  const float* b2        = (const float*)d_in[10];
  float* out = (float*)d_out;

  char* ws = (char*)d_ws;
  size_t off = 0;
  auto alloc = [&](size_t bytes) {
    void* p = ws + off;
    off += (bytes + 255) & ~(size_t)255;
    return p;
  };
  ushort* Mt    = (ushort*)alloc((size_t)D_ * D_ * 2);            // 1.18 MB
  float*  wbuf  = (float*) alloc((size_t)B_ * SP_ * 4);           // 256 KB
  float*  xbuf  = (float*) alloc((size_t)B_ * L_ * 4);            // 256 KB
  ushort* candb = (ushort*)alloc((size_t)B_ * SP_ * D_ * 2);      // 100.7 MB
  ushort* qm    = (ushort*)alloc((size_t)B_ * L_ * D_ * 2);       // 100.7 MB
  (void)ws_size; (void)in_sizes; (void)n_in; (void)out_size;

  k_mt  <<<(D_ / 4) * 3,        256, 0, stream>>>(WK, WQ, Mt);
  k_cand<<<(B_ * SP_) / 4,      256, 0, stream>>>(cand, cand_mask, WV, candb, wbuf);
  k_qm  <<<(B_ * L_ / 128) * 6, 256, 0, stream>>>(ctx, Mt, qm);
  k_attn<<<B_ * 4,              256, 0, stream>>>(qm, candb, wbuf, ctx_mask, xbuf);
  k_mlp <<<B_,                  128, 0, stream>>>(xbuf, W1, b1, W2, b2, out);
}

// Round 2
// 428.549 us; speedup vs baseline: 1.0394x; 1.0394x over previous
//
#include <hip/hip_runtime.h>
#include <hip/hip_bf16.h>
#include <stdint.h>

#define B_  256
#define L_  256
#define S_  253
#define SP_ 256   // padded S
#define D_  768
#define H_  128

typedef __bf16 bf16x8 __attribute__((ext_vector_type(8)));
typedef float  f32x4  __attribute__((ext_vector_type(4)));

__device__ __forceinline__ ushort f2bf(float f) {
  union { float f; uint32_t u; } v; v.f = f;
  uint32_t r = v.u + 0x7FFFu + ((v.u >> 16) & 1u);  // RNE
  return (ushort)(r >> 16);
}

__device__ __forceinline__ void gload16(const void* g, void* l) {
  __builtin_amdgcn_global_load_lds((const __attribute__((address_space(1))) void*)g,
                                   (__attribute__((address_space(3))) void*)l,
                                   16, 0, 0);
}

// ---------------- k0: Mt[i][j] = sum_t WK[i,t] * WQ[j,t]  (bf16 out) --------
__global__ __launch_bounds__(256) void k_mt(const float* __restrict__ WK,
                                            const float* __restrict__ WQ,
                                            ushort* __restrict__ Mt) {
  int bid = blockIdx.x;
  int i0 = (bid / 3) * 4;
  int j  = (bid % 3) * 256 + threadIdx.x;
  const float4* wq  = (const float4*)(WQ + (size_t)j * D_);
  const float4* wk0 = (const float4*)(WK + (size_t)(i0 + 0) * D_);
  const float4* wk1 = (const float4*)(WK + (size_t)(i0 + 1) * D_);
  const float4* wk2 = (const float4*)(WK + (size_t)(i0 + 2) * D_);
  const float4* wk3 = (const float4*)(WK + (size_t)(i0 + 3) * D_);
  float a0 = 0.f, a1 = 0.f, a2 = 0.f, a3 = 0.f;
#pragma unroll 4
  for (int t = 0; t < D_ / 4; ++t) {
    float4 q = wq[t];
    float4 k0 = wk0[t], k1 = wk1[t], k2 = wk2[t], k3 = wk3[t];
    a0 += q.x * k0.x + q.y * k0.y + q.z * k0.z + q.w * k0.w;
    a1 += q.x * k1.x + q.y * k1.y + q.z * k1.z + q.w * k1.w;
    a2 += q.x * k2.x + q.y * k2.y + q.z * k2.z + q.w * k2.w;
    a3 += q.x * k3.x + q.y * k3.y + q.z * k3.z + q.w * k3.w;
  }
  Mt[(size_t)(i0 + 0) * D_ + j] = f2bf(a0);
  Mt[(size_t)(i0 + 1) * D_ + j] = f2bf(a1);
  Mt[(size_t)(i0 + 2) * D_ + j] = f2bf(a2);
  Mt[(size_t)(i0 + 3) * D_ + j] = f2bf(a3);
}

// ---------------- k1: cand -> bf16 (padded), w[b,s] = mask * (cand . WV) ----
__global__ __launch_bounds__(256) void k_cand(const float* __restrict__ cand,
                                              const int* __restrict__ cand_mask,
                                              const float* __restrict__ WV,
                                              ushort* __restrict__ candb,
                                              float* __restrict__ wbuf) {
  int r = blockIdx.x * 4 + (threadIdx.x >> 6);  // padded row id, one wave per row
  int l = threadIdx.x & 63;
  int b = r >> 8, s = r & 255;
  float acc = 0.f;
  ushort* dst = candb + (size_t)r * D_;
  if (s < S_) {
    const float4* src = (const float4*)(cand + ((size_t)b * S_ + s) * D_);
    const float4* wv4 = (const float4*)WV;
#pragma unroll
    for (int i = 0; i < 3; ++i) {
      int d4 = i * 64 + l;  // float4 index within row (0..191)
      float4 c = src[d4];
      float4 v = wv4[d4];
      acc += c.x * v.x + c.y * v.y + c.z * v.z + c.w * v.w;
      ushort4 o;
      o.x = f2bf(c.x); o.y = f2bf(c.y); o.z = f2bf(c.z); o.w = f2bf(c.w);
      *(ushort4*)(dst + d4 * 4) = o;
    }
  } else {
    ushort4 z = {0, 0, 0, 0};
#pragma unroll
    for (int i = 0; i < 3; ++i) *(ushort4*)(dst + (i * 64 + l) * 4) = z;
  }
#pragma unroll
  for (int off = 32; off > 0; off >>= 1) acc += __shfl_down(acc, off, 64);
  if (l == 0) {
    float wv = 0.f;
    if (s < S_ && cand_mask[(size_t)b * S_ + s] != 0) wv = acc;
    wbuf[r] = wv;
  }
}

// ---------------- k2: qm[r][c] = sum_k ctx[r][k] * Mt[c][k]  (bf16 out) -----
// 128-row stripe per block; bn loop INSIDE the block so the f32 ctx panel is
// read from HBM once and re-read from cache (all 512 blocks co-resident ->
// whole ctx stays L3-warm). 4 waves (2x2), each wave 64x64 = 4x4 fragments.
__global__ __launch_bounds__(256) void k_qm(const float* __restrict__ ctx,
                                            const ushort* __restrict__ Mt,
                                            ushort* __restrict__ qm) {
  __shared__ __align__(16) ushort As[128 * 32];
  __shared__ __align__(16) ushort Bs[128 * 32];
  int bm = blockIdx.x;
  int row0 = bm * 128;
  int tid = threadIdx.x;
  int w = tid >> 6, l = tid & 63;
  int wr = w >> 1, wc = w & 1;

  // A staging: thread stages 16 f32 -> 16 bf16. row = tid/2, k-half = tid&1.
  int ar = tid >> 1;
  int ah = tid & 1;
  const float* actx = ctx + (size_t)(row0 + ar) * D_ + ah * 16;
  char* a_lds = (char*)As + ar * 64 + ah * 32;

  for (int bn = 0; bn < 6; ++bn) {
    int col0 = bn * 128;

    f32x4 acc[4][4];
#pragma unroll
    for (int m = 0; m < 4; ++m)
#pragma unroll
      for (int n = 0; n < 4; ++n) acc[m][n] = (f32x4){0.f, 0.f, 0.f, 0.f};

    for (int kt = 0; kt < D_; kt += 32) {
      if (bn | kt) __syncthreads();
      // B: async global->LDS, 2 insts/wave, 16 rows (1KB) each
#pragma unroll
      for (int g = 0; g < 2; ++g) {
        int grp = w * 2 + g;
        const ushort* gsrc = Mt + (size_t)(col0 + grp * 16 + (l >> 2)) * D_ + kt + (l & 3) * 8;
        gload16(gsrc, (char*)Bs + grp * 1024);
      }
      // A: reg-staged f32 -> bf16 (re-read per bn; cache-warm after bn=0)
      {
        const float4* ap = (const float4*)(actx + kt);
        float4 f0 = ap[0], f1 = ap[1], f2 = ap[2], f3 = ap[3];
        uint4 w0, w1;
        w0.x = (uint32_t)f2bf(f0.x) | ((uint32_t)f2bf(f0.y) << 16);
        w0.y = (uint32_t)f2bf(f0.z) | ((uint32_t)f2bf(f0.w) << 16);
        w0.z = (uint32_t)f2bf(f1.x) | ((uint32_t)f2bf(f1.y) << 16);
        w0.w = (uint32_t)f2bf(f1.z) | ((uint32_t)f2bf(f1.w) << 16);
        w1.x = (uint32_t)f2bf(f2.x) | ((uint32_t)f2bf(f2.y) << 16);
        w1.y = (uint32_t)f2bf(f2.z) | ((uint32_t)f2bf(f2.w) << 16);
        w1.z = (uint32_t)f2bf(f3.x) | ((uint32_t)f2bf(f3.y) << 16);
        w1.w = (uint32_t)f2bf(f3.z) | ((uint32_t)f2bf(f3.w) << 16);
        *(uint4*)(a_lds)      = w0;
        *(uint4*)(a_lds + 16) = w1;
      }
      __syncthreads();

      bf16x8 af[4], bfr[4];
#pragma unroll
      for (int m = 0; m < 4; ++m)
        af[m] = *(const bf16x8*)&As[(wr * 64 + m * 16 + (l & 15)) * 32 + (l >> 4) * 8];
#pragma unroll
      for (int n = 0; n < 4; ++n)
        bfr[n] = *(const bf16x8*)&Bs[(wc * 64 + n * 16 + (l & 15)) * 32 + (l >> 4) * 8];
#pragma unroll
      for (int m = 0; m < 4; ++m)
#pragma unroll
        for (int n = 0; n < 4; ++n)
          acc[m][n] = __builtin_amdgcn_mfma_f32_16x16x32_bf16(af[m], bfr[n], acc[m][n], 0, 0, 0);
    }

    int rbase = row0 + wr * 64;
    int cbase = col0 + wc * 64;
#pragma unroll
    for (int m = 0; m < 4; ++m)
#pragma unroll
      for (int n = 0; n < 4; ++n)
#pragma unroll
        for (int i = 0; i < 4; ++i) {
          int rr = rbase + m * 16 + (l >> 4) * 4 + i;
          int cc = cbase + n * 16 + (l & 15);
          qm[(size_t)rr * D_ + cc] = f2bf(acc[m][n][i]);
        }
  }
}

// ---------------- k3: logits -> sigmoid -> * w -> row-sum -> x --------------
// block = (b, 64-row L tile). BM=64, BN=256 (S padded), BK=32, 4 waves (1x4).
// XCD-bijective swizzle: the 4 lt-blocks of one b run adjacently on one XCD
// so candb[b] (393 KB) is fetched once and L2-hit 3x.
__global__ __launch_bounds__(256) void k_attn(const ushort* __restrict__ qm,
                                              const ushort* __restrict__ candb,
                                              const float* __restrict__ wbuf,
                                              const int* __restrict__ ctx_mask,
                                              float* __restrict__ xbuf) {
  __shared__ __align__(16) ushort As[64 * 32];
  __shared__ __align__(16) ushort Bs[256 * 32];
  __shared__ float w_lds[256];
  __shared__ float xpart[4][64];
  int bid0 = blockIdx.x;                    // 0..1023, grid % 8 == 0
  int nb = (bid0 & 7) * 128 + (bid0 >> 3);  // bijective XCD-chunked remap
  int b = nb >> 2, lt = nb & 3;
  int row0 = lt * 64;
  int tid = threadIdx.x, w = tid >> 6, l = tid & 63;
  w_lds[tid] = wbuf[(size_t)b * 256 + tid];

  f32x4 acc[4][4];
#pragma unroll
  for (int m = 0; m < 4; ++m)
#pragma unroll
    for (int n = 0; n < 4; ++n) acc[m][n] = (f32x4){0.f, 0.f, 0.f, 0.f};

  size_t arow = (size_t)b * 256 + row0;
  size_t brow = (size_t)b * 256;

  for (int kt = 0; kt < D_; kt += 32) {
    if (kt) __syncthreads();
    // A: 1 gload/wave (16 rows)
    {
      const ushort* gsrc = qm + (arow + w * 16 + (l >> 2)) * D_ + kt + (l & 3) * 8;
      gload16(gsrc, (char*)As + w * 1024);
    }
    // B: 4 gloads/wave (64 rows)
#pragma unroll
    for (int g = 0; g < 4; ++g) {
      int grp = w * 4 + g;
      const ushort* gsrc = candb + (brow + grp * 16 + (l >> 2)) * D_ + kt + (l & 3) * 8;
      gload16(gsrc, (char*)Bs + grp * 1024);
    }
    __syncthreads();

    bf16x8 af[4], bfr[4];
#pragma unroll
    for (int m = 0; m < 4; ++m)
      af[m] = *(const bf16x8*)&As[(m * 16 + (l & 15)) * 32 + (l >> 4) * 8];
#pragma unroll
    for (int n = 0; n < 4; ++n)
      bfr[n] = *(const bf16x8*)&Bs[(w * 64 + n * 16 + (l & 15)) * 32 + (l >> 4) * 8];
#pragma unroll
    for (int m = 0; m < 4; ++m)
#pragma unroll
      for (int n = 0; n < 4; ++n)
        acc[m][n] = __builtin_amdgcn_mfma_f32_16x16x32_bf16(af[m], bfr[n], acc[m][n], 0, 0, 0);
  }

  const float scale = 0.03608439182435161f;  // 1/sqrt(768)
  float rs[4][4];
#pragma unroll
  for (int m = 0; m < 4; ++m)
#pragma unroll
    for (int i = 0; i < 4; ++i) rs[m][i] = 0.f;

#pragma unroll
  for (int n = 0; n < 4; ++n) {
    float wcol = w_lds[w * 64 + n * 16 + (l & 15)];
#pragma unroll
    for (int m = 0; m < 4; ++m)
#pragma unroll
      for (int i = 0; i < 4; ++i) {
        float p = 1.f / (1.f + __expf(-acc[m][n][i] * scale));
        rs[m][i] += p * wcol;
      }
  }
#pragma unroll
  for (int m = 0; m < 4; ++m)
#pragma unroll
    for (int i = 0; i < 4; ++i) {
      float v = rs[m][i];
      v += __shfl_xor(v, 1, 64);
      v += __shfl_xor(v, 2, 64);
      v += __shfl_xor(v, 4, 64);
      v += __shfl_xor(v, 8, 64);
      rs[m][i] = v;
    }
  if ((l & 15) == 0) {
#pragma unroll
    for (int m = 0; m < 4; ++m)
#pragma unroll
      for (int i = 0; i < 4; ++i)
        xpart[w][m * 16 + (l >> 4) * 4 + i] = rs[m][i];
  }
  __syncthreads();
  if (tid < 64) {
    float xs = xpart[0][tid] + xpart[1][tid] + xpart[2][tid] + xpart[3][tid];
    int gm = ctx_mask[(size_t)b * 256 + row0 + tid];
    xbuf[(size_t)b * 256 + row0 + tid] = gm ? xs : 0.f;
  }
}

// ---------------- k4: y[b] = (x[b]^T W1 + b1) W2 + b2 ----------------------
__global__ __launch_bounds__(128) void k_mlp(const float* __restrict__ xbuf,
                                             const float* __restrict__ W1,
                                             const float* __restrict__ b1,
                                             const float* __restrict__ W2,
                                             const float* __restrict__ b2,
                                             float* __restrict__ out) {
  int b = blockIdx.x, t = threadIdx.x;
  __shared__ float xl[256];
  __shared__ float hl[128];
  xl[t]       = xbuf[(size_t)b * 256 + t];
  xl[t + 128] = xbuf[(size_t)b * 256 + 128 + t];
  __syncthreads();
  float acc = b1[t];
#pragma unroll 8
  for (int ll = 0; ll < 256; ++ll) acc += xl[ll] * W1[ll * H_ + t];
  hl[t] = acc;
  __syncthreads();
  if (t < 5) {
    float y = b2[t];
#pragma unroll 8
    for (int h = 0; h < H_; ++h) y += hl[h] * W2[h * 5 + t];
    out[(size_t)b * 5 + t] = y;
  }
}

extern "C" void kernel_launch(void* const* d_in, const int* in_sizes, int n_in,
                              void* d_out, int out_size, void* d_ws, size_t ws_size,
                              hipStream_t stream) {
  const float* ctx       = (const float*)d_in[0];
  const float* cand      = (const float*)d_in[1];
  const int*   ctx_mask  = (const int*)d_in[2];
  const int*   cand_mask = (const int*)d_in[3];
  const float* WK        = (const float*)d_in[4];
  const float* WQ        = (const float*)d_in[5];
  const float* WV        = (const float*)d_in[6];
  const float* W1        = (const float*)d_in[7];
  const float* b1        = (const float*)d_in[8];
  const float* W2        = (const float*)d_in[9];
  const float* b2        = (const float*)d_in[10];
  float* out = (float*)d_out;

  char* ws = (char*)d_ws;
  size_t off = 0;
  auto alloc = [&](size_t bytes) {
    void* p = ws + off;
    off += (bytes + 255) & ~(size_t)255;
    return p;
  };
  ushort* Mt    = (ushort*)alloc((size_t)D_ * D_ * 2);            // 1.18 MB
  float*  wbuf  = (float*) alloc((size_t)B_ * SP_ * 4);           // 256 KB
  float*  xbuf  = (float*) alloc((size_t)B_ * L_ * 4);            // 256 KB
  ushort* candb = (ushort*)alloc((size_t)B_ * SP_ * D_ * 2);      // 100.7 MB
  ushort* qm    = (ushort*)alloc((size_t)B_ * L_ * D_ * 2);       // 100.7 MB
  (void)ws_size; (void)in_sizes; (void)n_in; (void)out_size;

  k_mt  <<<(D_ / 4) * 3,   256, 0, stream>>>(WK, WQ, Mt);
  k_cand<<<(B_ * SP_) / 4, 256, 0, stream>>>(cand, cand_mask, WV, candb, wbuf);
  k_qm  <<<B_ * L_ / 128,  256, 0, stream>>>(ctx, Mt, qm);
  k_attn<<<B_ * 4,         256, 0, stream>>>(qm, candb, wbuf, ctx_mask, xbuf);
  k_mlp <<<B_,             128, 0, stream>>>(xbuf, W1, b1, W2, b2, out);
}

// Round 3
// 378.879 us; speedup vs baseline: 1.1757x; 1.1311x over previous
//
#include <hip/hip_runtime.h>
#include <hip/hip_bf16.h>
#include <stdint.h>

#define B_  256
#define L_  256
#define S_  253
#define SP_ 256   // padded S
#define D_  768
#define H_  128

typedef __bf16 bf16x8 __attribute__((ext_vector_type(8)));
typedef float  f32x4  __attribute__((ext_vector_type(4)));

__device__ __forceinline__ ushort f2bf(float f) {
  union { float f; uint32_t u; } v; v.f = f;
  uint32_t r = v.u + 0x7FFFu + ((v.u >> 16) & 1u);  // RNE
  return (ushort)(r >> 16);
}

__device__ __forceinline__ void gload16(const void* g, void* l) {
  __builtin_amdgcn_global_load_lds((const __attribute__((address_space(1))) void*)g,
                                   (__attribute__((address_space(3))) void*)l,
                                   16, 0, 0);
}

// ---------------- k0: Mt[i][j] = scale * sum_t WK[i,t] * WQ[j,t] (bf16) -----
// scale = 1/sqrt(768) folded here so k_attn's epilogue is a bare sigmoid.
__global__ __launch_bounds__(256) void k_mt(const float* __restrict__ WK,
                                            const float* __restrict__ WQ,
                                            ushort* __restrict__ Mt) {
  const float scale = 0.03608439182435161f;
  int bid = blockIdx.x;
  int i0 = (bid / 3) * 4;
  int j  = (bid % 3) * 256 + threadIdx.x;
  const float4* wq  = (const float4*)(WQ + (size_t)j * D_);
  const float4* wk0 = (const float4*)(WK + (size_t)(i0 + 0) * D_);
  const float4* wk1 = (const float4*)(WK + (size_t)(i0 + 1) * D_);
  const float4* wk2 = (const float4*)(WK + (size_t)(i0 + 2) * D_);
  const float4* wk3 = (const float4*)(WK + (size_t)(i0 + 3) * D_);
  float a0 = 0.f, a1 = 0.f, a2 = 0.f, a3 = 0.f;
#pragma unroll 4
  for (int t = 0; t < D_ / 4; ++t) {
    float4 q = wq[t];
    float4 k0 = wk0[t], k1 = wk1[t], k2 = wk2[t], k3 = wk3[t];
    a0 += q.x * k0.x + q.y * k0.y + q.z * k0.z + q.w * k0.w;
    a1 += q.x * k1.x + q.y * k1.y + q.z * k1.z + q.w * k1.w;
    a2 += q.x * k2.x + q.y * k2.y + q.z * k2.z + q.w * k2.w;
    a3 += q.x * k3.x + q.y * k3.y + q.z * k3.z + q.w * k3.w;
  }
  Mt[(size_t)(i0 + 0) * D_ + j] = f2bf(a0 * scale);
  Mt[(size_t)(i0 + 1) * D_ + j] = f2bf(a1 * scale);
  Mt[(size_t)(i0 + 2) * D_ + j] = f2bf(a2 * scale);
  Mt[(size_t)(i0 + 3) * D_ + j] = f2bf(a3 * scale);
}

// ---------------- k1: ctx f32 -> bf16, streaming ---------------------------
__global__ __launch_bounds__(256) void k_ctxb(const float* __restrict__ ctx,
                                              ushort* __restrict__ ctxb) {
  const int64_t n4 = (int64_t)B_ * L_ * D_ / 4;  // 12,582,912 float4s
  int64_t stride = (int64_t)gridDim.x * 256;
  for (int64_t i = (int64_t)blockIdx.x * 256 + threadIdx.x; i < n4; i += stride) {
    float4 c = ((const float4*)ctx)[i];
    ushort4 o;
    o.x = f2bf(c.x); o.y = f2bf(c.y); o.z = f2bf(c.z); o.w = f2bf(c.w);
    ((ushort4*)ctxb)[i] = o;
  }
}

// ---------------- k2: cand -> bf16 (padded), w[b,s] = mask * (cand . WV) ----
__global__ __launch_bounds__(256) void k_cand(const float* __restrict__ cand,
                                              const int* __restrict__ cand_mask,
                                              const float* __restrict__ WV,
                                              ushort* __restrict__ candb,
                                              float* __restrict__ wbuf) {
  int r = blockIdx.x * 4 + (threadIdx.x >> 6);  // padded row id, one wave per row
  int l = threadIdx.x & 63;
  int b = r >> 8, s = r & 255;
  float acc = 0.f;
  ushort* dst = candb + (size_t)r * D_;
  if (s < S_) {
    const float4* src = (const float4*)(cand + ((size_t)b * S_ + s) * D_);
    const float4* wv4 = (const float4*)WV;
#pragma unroll
    for (int i = 0; i < 3; ++i) {
      int d4 = i * 64 + l;
      float4 c = src[d4];
      float4 v = wv4[d4];
      acc += c.x * v.x + c.y * v.y + c.z * v.z + c.w * v.w;
      ushort4 o;
      o.x = f2bf(c.x); o.y = f2bf(c.y); o.z = f2bf(c.z); o.w = f2bf(c.w);
      *(ushort4*)(dst + d4 * 4) = o;
    }
  } else {
    ushort4 z = {0, 0, 0, 0};
#pragma unroll
    for (int i = 0; i < 3; ++i) *(ushort4*)(dst + (i * 64 + l) * 4) = z;
  }
#pragma unroll
  for (int off = 32; off > 0; off >>= 1) acc += __shfl_down(acc, off, 64);
  if (l == 0) {
    float wv = 0.f;
    if (s < S_ && cand_mask[(size_t)b * S_ + s] != 0) wv = acc;
    wbuf[r] = wv;
  }
}

// ---------------- k3: qm[r][c] = sum_k ctxb[r][k] * Mt[c][k]  (bf16 out) ----
// Pure m97 structure: 128x128 tile, BK=32, gload_lds(16B) for BOTH operands,
// 4 waves (2x2), 16 MFMA/wave/K-step. XCD-chunked swizzle keeps the 6
// bn-blocks of one A-panel adjacent on one XCD (A re-reads -> L2 hits).
__global__ __launch_bounds__(256) void k_qm(const ushort* __restrict__ ctxb,
                                            const ushort* __restrict__ Mt,
                                            ushort* __restrict__ qm) {
  __shared__ __align__(16) ushort As[128 * 32];
  __shared__ __align__(16) ushort Bs[128 * 32];
  int bid0 = blockIdx.x;              // 0..3071
  int xcd = bid0 & 7;
  int idx = bid0 >> 3;                // 0..383
  int bm = xcd * 64 + idx / 6;        // 0..511 (bijective)
  int bn = idx % 6;
  int row0 = bm * 128, col0 = bn * 128;
  int tid = threadIdx.x;
  int w = tid >> 6, l = tid & 63;
  int wr = w >> 1, wc = w & 1;

  f32x4 acc[4][4];
#pragma unroll
  for (int m = 0; m < 4; ++m)
#pragma unroll
    for (int n = 0; n < 4; ++n) acc[m][n] = (f32x4){0.f, 0.f, 0.f, 0.f};

  for (int kt = 0; kt < D_; kt += 32) {
    if (kt) __syncthreads();
#pragma unroll
    for (int g = 0; g < 2; ++g) {
      int grp = w * 2 + g;
      const ushort* asrc = ctxb + (size_t)(row0 + grp * 16 + (l >> 2)) * D_ + kt + (l & 3) * 8;
      gload16(asrc, (char*)As + grp * 1024);
      const ushort* bsrc = Mt + (size_t)(col0 + grp * 16 + (l >> 2)) * D_ + kt + (l & 3) * 8;
      gload16(bsrc, (char*)Bs + grp * 1024);
    }
    __syncthreads();

    bf16x8 af[4], bfr[4];
#pragma unroll
    for (int m = 0; m < 4; ++m)
      af[m] = *(const bf16x8*)&As[(wr * 64 + m * 16 + (l & 15)) * 32 + (l >> 4) * 8];
#pragma unroll
    for (int n = 0; n < 4; ++n)
      bfr[n] = *(const bf16x8*)&Bs[(wc * 64 + n * 16 + (l & 15)) * 32 + (l >> 4) * 8];
#pragma unroll
    for (int m = 0; m < 4; ++m)
#pragma unroll
      for (int n = 0; n < 4; ++n)
        acc[m][n] = __builtin_amdgcn_mfma_f32_16x16x32_bf16(af[m], bfr[n], acc[m][n], 0, 0, 0);
  }

  int rbase = row0 + wr * 64;
  int cbase = col0 + wc * 64;
#pragma unroll
  for (int m = 0; m < 4; ++m)
#pragma unroll
    for (int n = 0; n < 4; ++n)
#pragma unroll
      for (int i = 0; i < 4; ++i) {
        int rr = rbase + m * 16 + (l >> 4) * 4 + i;
        int cc = cbase + n * 16 + (l & 15);
        qm[(size_t)rr * D_ + cc] = f2bf(acc[m][n][i]);
      }
}

// ---------------- k4: logits -> sigmoid -> * w -> row-sum -> x --------------
// block = (b, 64-row L tile). BM=64, BN=256 (S padded), BK=32, 4 waves (1x4).
// XCD-bijective swizzle: the 4 lt-blocks of one b run adjacently on one XCD.
// Scale already folded into Mt -> bare sigmoid here.
__global__ __launch_bounds__(256) void k_attn(const ushort* __restrict__ qm,
                                              const ushort* __restrict__ candb,
                                              const float* __restrict__ wbuf,
                                              const int* __restrict__ ctx_mask,
                                              float* __restrict__ xbuf) {
  __shared__ __align__(16) ushort As[64 * 32];
  __shared__ __align__(16) ushort Bs[256 * 32];
  __shared__ float w_lds[256];
  __shared__ float xpart[4][64];
  int bid0 = blockIdx.x;                    // 0..1023
  int nb = (bid0 & 7) * 128 + (bid0 >> 3);  // bijective XCD-chunked remap
  int b = nb >> 2, lt = nb & 3;
  int row0 = lt * 64;
  int tid = threadIdx.x, w = tid >> 6, l = tid & 63;
  w_lds[tid] = wbuf[(size_t)b * 256 + tid];

  f32x4 acc[4][4];
#pragma unroll
  for (int m = 0; m < 4; ++m)
#pragma unroll
    for (int n = 0; n < 4; ++n) acc[m][n] = (f32x4){0.f, 0.f, 0.f, 0.f};

  size_t arow = (size_t)b * 256 + row0;
  size_t brow = (size_t)b * 256;

  for (int kt = 0; kt < D_; kt += 32) {
    if (kt) __syncthreads();
    {
      const ushort* gsrc = qm + (arow + w * 16 + (l >> 2)) * D_ + kt + (l & 3) * 8;
      gload16(gsrc, (char*)As + w * 1024);
    }
#pragma unroll
    for (int g = 0; g < 4; ++g) {
      int grp = w * 4 + g;
      const ushort* gsrc = candb + (brow + grp * 16 + (l >> 2)) * D_ + kt + (l & 3) * 8;
      gload16(gsrc, (char*)Bs + grp * 1024);
    }
    __syncthreads();

    bf16x8 af[4], bfr[4];
#pragma unroll
    for (int m = 0; m < 4; ++m)
      af[m] = *(const bf16x8*)&As[(m * 16 + (l & 15)) * 32 + (l >> 4) * 8];
#pragma unroll
    for (int n = 0; n < 4; ++n)
      bfr[n] = *(const bf16x8*)&Bs[(w * 64 + n * 16 + (l & 15)) * 32 + (l >> 4) * 8];
#pragma unroll
    for (int m = 0; m < 4; ++m)
#pragma unroll
      for (int n = 0; n < 4; ++n)
        acc[m][n] = __builtin_amdgcn_mfma_f32_16x16x32_bf16(af[m], bfr[n], acc[m][n], 0, 0, 0);
  }

  float rs[4][4];
#pragma unroll
  for (int m = 0; m < 4; ++m)
#pragma unroll
    for (int i = 0; i < 4; ++i) rs[m][i] = 0.f;

#pragma unroll
  for (int n = 0; n < 4; ++n) {
    float wcol = w_lds[w * 64 + n * 16 + (l & 15)];
#pragma unroll
    for (int m = 0; m < 4; ++m)
#pragma unroll
      for (int i = 0; i < 4; ++i) {
        float p = 1.f / (1.f + __expf(-acc[m][n][i]));
        rs[m][i] += p * wcol;
      }
  }
#pragma unroll
  for (int m = 0; m < 4; ++m)
#pragma unroll
    for (int i = 0; i < 4; ++i) {
      float v = rs[m][i];
      v += __shfl_xor(v, 1, 64);
      v += __shfl_xor(v, 2, 64);
      v += __shfl_xor(v, 4, 64);
      v += __shfl_xor(v, 8, 64);
      rs[m][i] = v;
    }
  if ((l & 15) == 0) {
#pragma unroll
    for (int m = 0; m < 4; ++m)
#pragma unroll
      for (int i = 0; i < 4; ++i)
        xpart[w][m * 16 + (l >> 4) * 4 + i] = rs[m][i];
  }
  __syncthreads();
  if (tid < 64) {
    float xs = xpart[0][tid] + xpart[1][tid] + xpart[2][tid] + xpart[3][tid];
    int gm = ctx_mask[(size_t)b * 256 + row0 + tid];
    xbuf[(size_t)b * 256 + row0 + tid] = gm ? xs : 0.f;
  }
}

// ---------------- k5: y[b] = (x[b]^T W1 + b1) W2 + b2 ----------------------
__global__ __launch_bounds__(128) void k_mlp(const float* __restrict__ xbuf,
                                             const float* __restrict__ W1,
                                             const float* __restrict__ b1,
                                             const float* __restrict__ W2,
                                             const float* __restrict__ b2,
                                             float* __restrict__ out) {
  int b = blockIdx.x, t = threadIdx.x;
  __shared__ float xl[256];
  __shared__ float hl[128];
  xl[t]       = xbuf[(size_t)b * 256 + t];
  xl[t + 128] = xbuf[(size_t)b * 256 + 128 + t];
  __syncthreads();
  float acc = b1[t];
#pragma unroll 8
  for (int ll = 0; ll < 256; ++ll) acc += xl[ll] * W1[ll * H_ + t];
  hl[t] = acc;
  __syncthreads();
  if (t < 5) {
    float y = b2[t];
#pragma unroll 8
    for (int h = 0; h < H_; ++h) y += hl[h] * W2[h * 5 + t];
    out[(size_t)b * 5 + t] = y;
  }
}

extern "C" void kernel_launch(void* const* d_in, const int* in_sizes, int n_in,
                              void* d_out, int out_size, void* d_ws, size_t ws_size,
                              hipStream_t stream) {
  const float* ctx       = (const float*)d_in[0];
  const float* cand      = (const float*)d_in[1];
  const int*   ctx_mask  = (const int*)d_in[2];
  const int*   cand_mask = (const int*)d_in[3];
  const float* WK        = (const float*)d_in[4];
  const float* WQ        = (const float*)d_in[5];
  const float* WV        = (const float*)d_in[6];
  const float* W1        = (const float*)d_in[7];
  const float* b1        = (const float*)d_in[8];
  const float* W2        = (const float*)d_in[9];
  const float* b2        = (const float*)d_in[10];
  float* out = (float*)d_out;

  char* ws = (char*)d_ws;
  size_t off = 0;
  auto alloc = [&](size_t bytes) {
    void* p = ws + off;
    off += (bytes + 255) & ~(size_t)255;
    return p;
  };
  ushort* Mt    = (ushort*)alloc((size_t)D_ * D_ * 2);            // 1.18 MB
  float*  wbuf  = (float*) alloc((size_t)B_ * SP_ * 4);           // 256 KB
  float*  xbuf  = (float*) alloc((size_t)B_ * L_ * 4);            // 256 KB
  ushort* candb = (ushort*)alloc((size_t)B_ * SP_ * D_ * 2);      // 100.7 MB
  ushort* qm    = (ushort*)alloc((size_t)B_ * L_ * D_ * 2);       // 100.7 MB
  ushort* ctxb  = (ushort*)alloc((size_t)B_ * L_ * D_ * 2);       // 100.7 MB
  (void)ws_size; (void)in_sizes; (void)n_in; (void)out_size;

  k_mt  <<<(D_ / 4) * 3,   256, 0, stream>>>(WK, WQ, Mt);
  k_ctxb<<<2048,           256, 0, stream>>>(ctx, ctxb);
  k_cand<<<(B_ * SP_) / 4, 256, 0, stream>>>(cand, cand_mask, WV, candb, wbuf);
  k_qm  <<<B_ * L_ / 128 * 6, 256, 0, stream>>>(ctxb, Mt, qm);
  k_attn<<<B_ * 4,         256, 0, stream>>>(qm, candb, wbuf, ctx_mask, xbuf);
  k_mlp <<<B_,             128, 0, stream>>>(xbuf, W1, b1, W2, b2, out);
}